// Round 2
// baseline (249.018 us; speedup 1.0000x reference)
//
#include <hip/hip_runtime.h>
#include <hip/hip_bf16.h>

typedef __attribute__((ext_vector_type(4))) float          fx4;
typedef __attribute__((ext_vector_type(8))) __bf16         bfx8;
typedef __attribute__((ext_vector_type(8))) unsigned short usx8;
typedef __attribute__((ext_vector_type(4))) unsigned short usx4;

#define TLEN 2048
#define ROWS 4096   /* B*T */
#define D    1024

__device__ __forceinline__ float bf2f(unsigned short u) {
    union { unsigned int i; float f; } v; v.i = ((unsigned int)u) << 16; return v.f;
}
__device__ __forceinline__ unsigned short f2bf(float f) {
    union { float f; unsigned int i; } v; v.f = f;
    unsigned int r = v.i + 0x7fffu + ((v.i >> 16) & 1u);
    return (unsigned short)(r >> 16);
}
__device__ __forceinline__ void gload_lds16(const unsigned short* g, unsigned short* l) {
    __builtin_amdgcn_global_load_lds((const __attribute__((address_space(1))) void*)g,
                                     (__attribute__((address_space(3))) void*)l, 16, 0, 0);
}

// ---------------- LayerNorm: fp32 x -> bf16 h ----------------
__global__ __launch_bounds__(256) void ln_kernel(const float* __restrict__ x,
                                                 const float* __restrict__ g,
                                                 const float* __restrict__ bta,
                                                 unsigned short* __restrict__ hout) {
    const int row = blockIdx.x, tid = threadIdx.x;
    fx4 v = ((const fx4*)(x + (size_t)row * D))[tid];
    float s  = v[0] + v[1] + v[2] + v[3];
    float s2 = v[0]*v[0] + v[1]*v[1] + v[2]*v[2] + v[3]*v[3];
    #pragma unroll
    for (int mk = 32; mk >= 1; mk >>= 1) { s += __shfl_xor(s, mk); s2 += __shfl_xor(s2, mk); }
    __shared__ float red[8];
    const int wave = tid >> 6, lane = tid & 63;
    if (lane == 0) { red[wave] = s; red[4 + wave] = s2; }
    __syncthreads();
    s  = red[0] + red[1] + red[2] + red[3];
    s2 = red[4] + red[5] + red[6] + red[7];
    float mu   = s * (1.0f / D);
    float var  = s2 * (1.0f / D) - mu * mu;
    float rstd = rsqrtf(var + 1e-5f);
    fx4 gv = ((const fx4*)g)[tid];
    fx4 bv = ((const fx4*)bta)[tid];
    usx4 o;
    #pragma unroll
    for (int j = 0; j < 4; j++) o[j] = f2bf((v[j] - mu) * rstd * gv[j] + bv[j]);
    ((usx4*)hout)[(size_t)row * 256 + tid] = o;
}

// ---------------- Weight convert: fp32 -> bf16, wq|wk|wv concat ----------------
__device__ __forceinline__ usx4 cvt4(fx4 a) {
    usx4 o;
    #pragma unroll
    for (int j = 0; j < 4; j++) o[j] = f2bf(a[j]);
    return o;
}
__global__ __launch_bounds__(256) void wconv_kernel(const float* __restrict__ wq, const float* __restrict__ wk,
                                                    const float* __restrict__ wv, const float* __restrict__ wo,
                                                    unsigned short* __restrict__ wqkv,
                                                    unsigned short* __restrict__ wob) {
    const int i = blockIdx.x * 256 + threadIdx.x;   // usx4 units, 262144 per matrix
    ((usx4*)wqkv)[i]          = cvt4(((const fx4*)wq)[i]);
    ((usx4*)wqkv)[262144 + i] = cvt4(((const fx4*)wk)[i]);
    ((usx4*)wqkv)[524288 + i] = cvt4(((const fx4*)wv)[i]);
    ((usx4*)wob)[i]           = cvt4(((const fx4*)wo)[i]);
}

// ---------------- GEMM C[M,N] = A[M,K] * B[N,K]^T  (bf16 in, bf16/f32 out) ----------------
// m97 structure: 128x128 tile, BK=32, 4 waves (2x2), global_load_lds width 16.
template<int OUTF32>
__global__ __launch_bounds__(256) void gemm_bt(const unsigned short* __restrict__ A,
                                               const unsigned short* __restrict__ B,
                                               void* __restrict__ C, int ldc) {
    constexpr int K = 1024;
    __shared__ __align__(16) unsigned short As[128 * 32];
    __shared__ __align__(16) unsigned short Bs[128 * 32];
    const int tid = threadIdx.x, lane = tid & 63, wave = tid >> 6;
    const int fr = lane & 15, fq = lane >> 4;
    const int bm = blockIdx.x, bn = blockIdx.y;
    const int wr = wave >> 1, wc = wave & 1;

    const int str0 = wave * 32 + (lane >> 2);   // staging row (c=0); c=1 adds 16
    const int stc  = (lane & 3) * 8;            // staging col (bf16 elems)
    const unsigned short* Ab = A + (size_t)(bm * 128) * K;
    const unsigned short* Bb = B + (size_t)(bn * 128) * K;

    fx4 acc[4][4];
    #pragma unroll
    for (int m = 0; m < 4; m++)
        #pragma unroll
        for (int n = 0; n < 4; n++) acc[m][n] = (fx4)0.0f;

    for (int kt = 0; kt < K; kt += 32) {
        gload_lds16(Ab + (size_t)str0 * K + kt + stc,        &As[str0 * 32 + stc]);
        gload_lds16(Ab + (size_t)(str0 + 16) * K + kt + stc, &As[(str0 + 16) * 32 + stc]);
        gload_lds16(Bb + (size_t)str0 * K + kt + stc,        &Bs[str0 * 32 + stc]);
        gload_lds16(Bb + (size_t)(str0 + 16) * K + kt + stc, &Bs[(str0 + 16) * 32 + stc]);
        __syncthreads();
        bfx8 aF[4], bF[4];
        #pragma unroll
        for (int m = 0; m < 4; m++) aF[m] = *(const bfx8*)&As[(wr * 64 + m * 16 + fr) * 32 + fq * 8];
        #pragma unroll
        for (int n = 0; n < 4; n++) bF[n] = *(const bfx8*)&Bs[(wc * 64 + n * 16 + fr) * 32 + fq * 8];
        #pragma unroll
        for (int m = 0; m < 4; m++)
            #pragma unroll
            for (int n = 0; n < 4; n++)
                acc[m][n] = __builtin_amdgcn_mfma_f32_16x16x32_bf16(aF[m], bF[n], acc[m][n], 0, 0, 0);
        __syncthreads();
    }

    const int row0 = bm * 128 + wr * 64 + fq * 4;
    const int col0 = bn * 128 + wc * 64 + fr;
    #pragma unroll
    for (int m = 0; m < 4; m++)
        #pragma unroll
        for (int n = 0; n < 4; n++)
            #pragma unroll
            for (int j = 0; j < 4; j++) {
                int r = row0 + m * 16 + j, c = col0 + n * 16;
                if (OUTF32) ((float*)C)[(size_t)r * ldc + c] = acc[m][n][j];
                else        ((unsigned short*)C)[(size_t)r * ldc + c] = f2bf(acc[m][n][j]);
            }
}

// ---------------- RoPE in-place on q,k (q also pre-scaled by 0.125*log2e) ----------------
__global__ __launch_bounds__(256) void rope_kernel(unsigned short* __restrict__ qkv,
                                                   const float* __restrict__ cosT,
                                                   const float* __restrict__ sinT) {
    int idx = blockIdx.x * 256 + threadIdx.x;   // 0 .. 2M-1 (4096 rows * 512 pairs)
    int row = idx >> 9;
    int p   = idx & 511;
    int head = p >> 5, pi = p & 31;
    int t = row & (TLEN - 1);
    float c = cosT[t * 32 + pi], s = sinT[t * 32 + pi];
    size_t qoff = (size_t)row * 3072 + head * 64 + pi * 2;
    const float QS = 0.125f * 1.44269504088896f;   // scale * log2(e): softmax via exp2 is exact
    unsigned int uq = *(const unsigned int*)&qkv[qoff];
    float x0 = bf2f((unsigned short)(uq & 0xffff));
    float x1 = bf2f((unsigned short)(uq >> 16));
    unsigned int r0 = f2bf((x0 * c - x1 * s) * QS);
    unsigned int r1 = f2bf((x0 * s + x1 * c) * QS);
    *(unsigned int*)&qkv[qoff] = r0 | (r1 << 16);
    size_t koff = qoff + 1024;
    unsigned int uk = *(const unsigned int*)&qkv[koff];
    x0 = bf2f((unsigned short)(uk & 0xffff));
    x1 = bf2f((unsigned short)(uk >> 16));
    r0 = f2bf(x0 * c - x1 * s);
    r1 = f2bf(x0 * s + x1 * c);
    *(unsigned int*)&qkv[koff] = r0 | (r1 << 16);
}

// ---------------- Flash attention (full, non-causal), bf16 MFMA ----------------
// grid = (T/64, B*H); 256 threads = 4 waves; wave handles 16 q-rows; KVBLK=64.
__global__ __launch_bounds__(256) void attn_kernel(const unsigned short* __restrict__ qkv,
                                                   unsigned short* __restrict__ ao) {
    const int qt = blockIdx.x, bh = blockIdx.y;
    const int b = bh >> 4, hh = bh & 15;
    const int tid = threadIdx.x, lane = tid & 63, wave = tid >> 6;
    const int fr = lane & 15, fq = lane >> 4;

    __shared__ __align__(16) unsigned short sVt[64][72];     // V^T tile [d][kv], +8 pad
    __shared__ __align__(16) unsigned short sP[4][16][72];   // per-wave P [q][kv], +8 pad

    const size_t rs = 3072;
    const unsigned short* qb = qkv + (size_t)b * TLEN * rs + hh * 64;
    const unsigned short* kb = qb + 1024;
    const unsigned short* vb = qb + 2048;

    bfx8 qF[2];
    {
        int qrow = qt * 64 + wave * 16 + fr;
        const unsigned short* qp = qb + (size_t)qrow * rs + fq * 8;
        qF[0] = *(const bfx8*)qp;
        qF[1] = *(const bfx8*)(qp + 32);
    }

    float m_run[4] = {-1e30f, -1e30f, -1e30f, -1e30f};
    float l_run[4] = {0.f, 0.f, 0.f, 0.f};
    fx4 oacc[4];
    #pragma unroll
    for (int d = 0; d < 4; d++) oacc[d] = (fx4)0.0f;

    for (int kt = 0; kt < TLEN; kt += 64) {
        __syncthreads();   // previous tile's Vt reads complete
        // stage V^T: kv-major lanes -> conflict-free ds writes
        {
            int kvloc = tid & 63;
            int d0 = (tid >> 6) * 16;
            const unsigned short* vsrc = vb + (size_t)(kt + kvloc) * rs + d0;
            usx8 v0 = *(const usx8*)vsrc;
            usx8 v1 = *(const usx8*)(vsrc + 8);
            #pragma unroll
            for (int j = 0; j < 8; j++) {
                sVt[d0 + j][kvloc]     = v0[j];
                sVt[d0 + 8 + j][kvloc] = v1[j];
            }
        }
        // S = q k^T (pre-scaled into exp2 domain); K frags direct from global (L2)
        fx4 sacc[4];
        #pragma unroll
        for (int n = 0; n < 4; n++) sacc[n] = (fx4)0.0f;
        #pragma unroll
        for (int s = 0; s < 2; s++)
            #pragma unroll
            for (int n = 0; n < 4; n++) {
                bfx8 kF = *(const bfx8*)(kb + (size_t)(kt + n * 16 + fr) * rs + s * 32 + fq * 8);
                sacc[n] = __builtin_amdgcn_mfma_f32_16x16x32_bf16(qF[s], kF, sacc[n], 0, 0, 0);
            }
        // online softmax (rows fq*4+j, cols fr across 16-lane group)
        float pmax[4], pv[4][4];
        #pragma unroll
        for (int j = 0; j < 4; j++)
            pmax[j] = fmaxf(fmaxf(sacc[0][j], sacc[1][j]), fmaxf(sacc[2][j], sacc[3][j]));
        #pragma unroll
        for (int mk = 1; mk < 16; mk <<= 1)
            #pragma unroll
            for (int j = 0; j < 4; j++) pmax[j] = fmaxf(pmax[j], __shfl_xor(pmax[j], mk));
        float scal[4];
        #pragma unroll
        for (int j = 0; j < 4; j++) {
            float mn = fmaxf(m_run[j], pmax[j]);
            scal[j] = exp2f(m_run[j] - mn);
            m_run[j] = mn;
        }
        float psum[4] = {0.f, 0.f, 0.f, 0.f};
        #pragma unroll
        for (int n = 0; n < 4; n++)
            #pragma unroll
            for (int j = 0; j < 4; j++) {
                float p = exp2f(sacc[n][j] - m_run[j]);
                pv[n][j] = p; psum[j] += p;
            }
        #pragma unroll
        for (int mk = 1; mk < 16; mk <<= 1)
            #pragma unroll
            for (int j = 0; j < 4; j++) psum[j] += __shfl_xor(psum[j], mk);
        #pragma unroll
        for (int j = 0; j < 4; j++) l_run[j] = l_run[j] * scal[j] + psum[j];
        #pragma unroll
        for (int n = 0; n < 4; n++)
            #pragma unroll
            for (int j = 0; j < 4; j++) sP[wave][fq * 4 + j][n * 16 + fr] = f2bf(pv[n][j]);
        #pragma unroll
        for (int d = 0; d < 4; d++)
            #pragma unroll
            for (int j = 0; j < 4; j++) oacc[d][j] *= scal[j];
        __syncthreads();   // Vt staged + P written
        // O += P * V
        bfx8 pF0 = *(const bfx8*)&sP[wave][fr][fq * 8];
        bfx8 pF1 = *(const bfx8*)&sP[wave][fr][32 + fq * 8];
        #pragma unroll
        for (int d = 0; d < 4; d++) {
            bfx8 vF0 = *(const bfx8*)&sVt[d * 16 + fr][fq * 8];
            bfx8 vF1 = *(const bfx8*)&sVt[d * 16 + fr][32 + fq * 8];
            oacc[d] = __builtin_amdgcn_mfma_f32_16x16x32_bf16(pF0, vF0, oacc[d], 0, 0, 0);
            oacc[d] = __builtin_amdgcn_mfma_f32_16x16x32_bf16(pF1, vF1, oacc[d], 0, 0, 0);
        }
    }
    float inv[4];
    #pragma unroll
    for (int j = 0; j < 4; j++) inv[j] = 1.0f / l_run[j];
    #pragma unroll
    for (int d = 0; d < 4; d++)
        #pragma unroll
        for (int j = 0; j < 4; j++) {
            int qrow = qt * 64 + wave * 16 + fq * 4 + j;
            int col  = hh * 64 + d * 16 + fr;
            ao[(size_t)(b * TLEN + qrow) * 1024 + col] = f2bf(oacc[d][j] * inv[j]);
        }
}

extern "C" void kernel_launch(void* const* d_in, const int* in_sizes, int n_in,
                              void* d_out, int out_size, void* d_ws, size_t ws_size,
                              hipStream_t stream) {
    const float* x    = (const float*)d_in[0];
    const float* wq   = (const float*)d_in[1];
    const float* wk   = (const float*)d_in[2];
    const float* wv   = (const float*)d_in[3];
    const float* wo   = (const float*)d_in[4];
    const float* lng  = (const float*)d_in[5];
    const float* lnb  = (const float*)d_in[6];
    const float* cosT = (const float*)d_in[7];
    const float* sinT = (const float*)d_in[8];

    char* ws = (char*)d_ws;
    unsigned short* wqkv = (unsigned short*)(ws);                // 6 MB  [3072][1024] bf16
    unsigned short* wob  = (unsigned short*)(ws + (6u << 20));   // 2 MB  [1024][1024] bf16
    unsigned short* hbuf = (unsigned short*)(ws + (8u << 20));   // 8 MB  [4096][1024] bf16
    unsigned short* qkv  = (unsigned short*)(ws + (16u << 20));  // 24 MB [4096][3072] bf16
    unsigned short* ao   = (unsigned short*)(ws + (8u << 20));   // aliases hbuf (dead after QKV GEMM)

    ln_kernel<<<ROWS, 256, 0, stream>>>(x, lng, lnb, hbuf);
    wconv_kernel<<<1024, 256, 0, stream>>>(wq, wk, wv, wo, wqkv, wob);
    gemm_bt<0><<<dim3(32, 24), 256, 0, stream>>>(hbuf, wqkv, qkv, 3072);
    rope_kernel<<<8192, 256, 0, stream>>>(qkv, cosT, sinT);
    attn_kernel<<<dim3(32, 32), 256, 0, stream>>>(qkv, ao);
    gemm_bt<1><<<dim3(32, 8), 256, 0, stream>>>(ao, wob, (float*)d_out, 1024);
}

// Round 3
// 173.607 us; speedup vs baseline: 1.4344x; 1.4344x over previous
//
#include <hip/hip_runtime.h>
#include <hip/hip_bf16.h>

typedef __attribute__((ext_vector_type(4))) float          fx4;
typedef __attribute__((ext_vector_type(8))) __bf16         bfx8;
typedef __attribute__((ext_vector_type(8))) unsigned short usx8;
typedef __attribute__((ext_vector_type(4))) unsigned short usx4;

#define TLEN 2048
#define ROWS 4096   /* B*T */
#define D    1024

__device__ __forceinline__ float bf2f(unsigned short u) {
    union { unsigned int i; float f; } v; v.i = ((unsigned int)u) << 16; return v.f;
}
__device__ __forceinline__ unsigned short f2bf(float f) {
    union { float f; unsigned int i; } v; v.f = f;
    unsigned int r = v.i + 0x7fffu + ((v.i >> 16) & 1u);
    return (unsigned short)(r >> 16);
}
__device__ __forceinline__ void gload_lds16(const unsigned short* g, unsigned short* l) {
    __builtin_amdgcn_global_load_lds((const __attribute__((address_space(1))) void*)g,
                                     (__attribute__((address_space(3))) void*)l, 16, 0, 0);
}

// ---------------- LayerNorm: fp32 x -> bf16 h ----------------
__global__ __launch_bounds__(256) void ln_kernel(const float* __restrict__ x,
                                                 const float* __restrict__ g,
                                                 const float* __restrict__ bta,
                                                 unsigned short* __restrict__ hout) {
    const int row = blockIdx.x, tid = threadIdx.x;
    fx4 v = ((const fx4*)(x + (size_t)row * D))[tid];
    float s  = v[0] + v[1] + v[2] + v[3];
    float s2 = v[0]*v[0] + v[1]*v[1] + v[2]*v[2] + v[3]*v[3];
    #pragma unroll
    for (int mk = 32; mk >= 1; mk >>= 1) { s += __shfl_xor(s, mk); s2 += __shfl_xor(s2, mk); }
    __shared__ float red[8];
    const int wave = tid >> 6, lane = tid & 63;
    if (lane == 0) { red[wave] = s; red[4 + wave] = s2; }
    __syncthreads();
    s  = red[0] + red[1] + red[2] + red[3];
    s2 = red[4] + red[5] + red[6] + red[7];
    float mu   = s * (1.0f / D);
    float var  = s2 * (1.0f / D) - mu * mu;
    float rstd = rsqrtf(var + 1e-5f);
    fx4 gv = ((const fx4*)g)[tid];
    fx4 bv = ((const fx4*)bta)[tid];
    usx4 o;
    #pragma unroll
    for (int j = 0; j < 4; j++) o[j] = f2bf((v[j] - mu) * rstd * gv[j] + bv[j]);
    ((usx4*)hout)[(size_t)row * 256 + tid] = o;
}

// ---------------- Weight convert: fp32 -> bf16, wq|wk|wv concat ----------------
__device__ __forceinline__ usx4 cvt4(fx4 a) {
    usx4 o;
    #pragma unroll
    for (int j = 0; j < 4; j++) o[j] = f2bf(a[j]);
    return o;
}
__global__ __launch_bounds__(256) void wconv_kernel(const float* __restrict__ wq, const float* __restrict__ wk,
                                                    const float* __restrict__ wv, const float* __restrict__ wo,
                                                    unsigned short* __restrict__ wqkv,
                                                    unsigned short* __restrict__ wob) {
    const int i = blockIdx.x * 256 + threadIdx.x;   // usx4 units, 262144 per matrix
    ((usx4*)wqkv)[i]          = cvt4(((const fx4*)wq)[i]);
    ((usx4*)wqkv)[262144 + i] = cvt4(((const fx4*)wk)[i]);
    ((usx4*)wqkv)[524288 + i] = cvt4(((const fx4*)wv)[i]);
    ((usx4*)wob)[i]           = cvt4(((const fx4*)wo)[i]);
}

// ---------------- GEMM C[M,N] = A[M,K] * B[N,K]^T  (bf16 in, bf16/f32 out) ----------------
// m97 structure: 128x128 tile, BK=32, 4 waves (2x2), global_load_lds width 16.
template<int OUTF32>
__global__ __launch_bounds__(256) void gemm_bt(const unsigned short* __restrict__ A,
                                               const unsigned short* __restrict__ B,
                                               void* __restrict__ C, int ldc) {
    constexpr int K = 1024;
    __shared__ __align__(16) unsigned short As[128 * 32];
    __shared__ __align__(16) unsigned short Bs[128 * 32];
    const int tid = threadIdx.x, lane = tid & 63, wave = tid >> 6;
    const int fr = lane & 15, fq = lane >> 4;
    const int bm = blockIdx.x, bn = blockIdx.y;
    const int wr = wave >> 1, wc = wave & 1;

    const int str0 = wave * 32 + (lane >> 2);   // staging row (c=0); c=1 adds 16
    const int stc  = (lane & 3) * 8;            // staging col (bf16 elems)
    const unsigned short* Ab = A + (size_t)(bm * 128) * K;
    const unsigned short* Bb = B + (size_t)(bn * 128) * K;

    fx4 acc[4][4];
    #pragma unroll
    for (int m = 0; m < 4; m++)
        #pragma unroll
        for (int n = 0; n < 4; n++) acc[m][n] = (fx4)0.0f;

    for (int kt = 0; kt < K; kt += 32) {
        gload_lds16(Ab + (size_t)str0 * K + kt + stc,        &As[str0 * 32 + stc]);
        gload_lds16(Ab + (size_t)(str0 + 16) * K + kt + stc, &As[(str0 + 16) * 32 + stc]);
        gload_lds16(Bb + (size_t)str0 * K + kt + stc,        &Bs[str0 * 32 + stc]);
        gload_lds16(Bb + (size_t)(str0 + 16) * K + kt + stc, &Bs[(str0 + 16) * 32 + stc]);
        __syncthreads();
        bfx8 aF[4], bF[4];
        #pragma unroll
        for (int m = 0; m < 4; m++) aF[m] = *(const bfx8*)&As[(wr * 64 + m * 16 + fr) * 32 + fq * 8];
        #pragma unroll
        for (int n = 0; n < 4; n++) bF[n] = *(const bfx8*)&Bs[(wc * 64 + n * 16 + fr) * 32 + fq * 8];
        #pragma unroll
        for (int m = 0; m < 4; m++)
            #pragma unroll
            for (int n = 0; n < 4; n++)
                acc[m][n] = __builtin_amdgcn_mfma_f32_16x16x32_bf16(aF[m], bF[n], acc[m][n], 0, 0, 0);
        __syncthreads();
    }

    const int row0 = bm * 128 + wr * 64 + fq * 4;
    const int col0 = bn * 128 + wc * 64 + fr;
    #pragma unroll
    for (int m = 0; m < 4; m++)
        #pragma unroll
        for (int n = 0; n < 4; n++)
            #pragma unroll
            for (int j = 0; j < 4; j++) {
                int r = row0 + m * 16 + j, c = col0 + n * 16;
                if (OUTF32) ((float*)C)[(size_t)r * ldc + c] = acc[m][n][j];
                else        ((unsigned short*)C)[(size_t)r * ldc + c] = f2bf(acc[m][n][j]);
            }
}

// ---------------- RoPE in-place on q,k (q also pre-scaled by 0.125*log2e) ----------------
__global__ __launch_bounds__(256) void rope_kernel(unsigned short* __restrict__ qkv,
                                                   const float* __restrict__ cosT,
                                                   const float* __restrict__ sinT) {
    int idx = blockIdx.x * 256 + threadIdx.x;   // 0 .. 2M-1 (4096 rows * 512 pairs)
    int row = idx >> 9;
    int p   = idx & 511;
    int head = p >> 5, pi = p & 31;
    int t = row & (TLEN - 1);
    float c = cosT[t * 32 + pi], s = sinT[t * 32 + pi];
    size_t qoff = (size_t)row * 3072 + head * 64 + pi * 2;
    const float QS = 0.125f * 1.44269504088896f;   // scale * log2(e): softmax via exp2 is exact
    unsigned int uq = *(const unsigned int*)&qkv[qoff];
    float x0 = bf2f((unsigned short)(uq & 0xffff));
    float x1 = bf2f((unsigned short)(uq >> 16));
    unsigned int r0 = f2bf((x0 * c - x1 * s) * QS);
    unsigned int r1 = f2bf((x0 * s + x1 * c) * QS);
    *(unsigned int*)&qkv[qoff] = r0 | (r1 << 16);
    size_t koff = qoff + 1024;
    unsigned int uk = *(const unsigned int*)&qkv[koff];
    x0 = bf2f((unsigned short)(uk & 0xffff));
    x1 = bf2f((unsigned short)(uk >> 16));
    r0 = f2bf(x0 * c - x1 * s);
    r1 = f2bf(x0 * s + x1 * c);
    *(unsigned int*)&qkv[koff] = r0 | (r1 << 16);
}

// ---------------- Flash attention (full, non-causal), bf16 MFMA ----------------
// grid = (T/64, B*H); 256 threads = 4 waves; wave owns 16 q-rows; KVBLK=64.
// Swapped-operand QK^T (lane-local softmax) + in-register P butterfly + swapped PV.
// K staged via global_load_lds with both-sides XOR swizzle; K/V double-buffered.
__global__ __launch_bounds__(256) void attn_kernel(const unsigned short* __restrict__ qkv,
                                                   unsigned short* __restrict__ ao) {
    const int qt = blockIdx.x, bh = blockIdx.y;
    const int b = bh >> 4, hh = bh & 15;
    const int tid = threadIdx.x, lane = tid & 63, wave = tid >> 6;
    const int fr = lane & 15, fq = lane >> 4;

    __shared__ __align__(16) unsigned short sK[2][64 * 64];   // swizzled, linear-dest for gload_lds
    __shared__ __align__(16) unsigned short sVt[2][64][72];   // V^T [d][kv], +8 pad

    const size_t rs = 3072;
    const unsigned short* qb = qkv + (size_t)b * TLEN * rs + hh * 64;
    const unsigned short* kb = qb + 1024;
    const unsigned short* vb = qb + 2048;

    // Q fragments (B-operand: lane fr = q-row, k = fq*8 within 32-step)
    bfx8 qF[2];
    {
        int qrow = qt * 64 + wave * 16 + fr;
        const unsigned short* qp = qb + (size_t)qrow * rs + fq * 8;
        qF[0] = *(const bfx8*)qp;
        qF[1] = *(const bfx8*)(qp + 32);
    }

    // K staging geometry: wave stages row-groups rg=wave*2+{0,1} (8 rows each).
    // LDS dest linear (base + lane*16B); global source col pre-swizzled so that
    // read addr (row*128 + g*16) ^ ((row&7)<<4) lands on the right data.
    const int srow = lane >> 3;                    // row within 8-row group
    const int scol = ((lane & 7) ^ srow) * 8;      // pre-swizzled source col (shorts)
    const int vkv = tid & 63;                      // V stage: kv row
    const int vd0 = (tid >> 6) * 16;               // V stage: d block

    // ---- prologue: stage tile 0 into buf 0
    {
        #pragma unroll
        for (int i = 0; i < 2; i++) {
            int rg = wave * 2 + i;
            gload_lds16(kb + (size_t)(rg * 8 + srow) * rs + scol, &sK[0][rg * 512 + lane * 8]);
        }
        const unsigned short* vsrc = vb + (size_t)vkv * rs + vd0;
        usx8 v0 = *(const usx8*)vsrc;
        usx8 v1 = *(const usx8*)(vsrc + 8);
        #pragma unroll
        for (int j = 0; j < 8; j++) {
            sVt[0][vd0 + j][vkv]     = v0[j];
            sVt[0][vd0 + 8 + j][vkv] = v1[j];
        }
    }

    float m_run = -1e30f, l_run = 0.0f;
    fx4 oacc[4];
    #pragma unroll
    for (int db = 0; db < 4; db++) oacc[db] = (fx4)0.0f;

    const int f1 = (lane >> 5) & 1, f0 = (lane >> 4) & 1;

    for (int t = 0; t < 32; ++t) {
        const int buf = t & 1;
        __syncthreads();   // buf staging drained (vmcnt+lgkm at barrier); prior reads of buf^1 done

        // ---- prefetch next tile (issue early; writes later under the MFMA/softmax)
        usx8 pv0, pv1;
        const bool pf = (t + 1 < 32);
        if (pf) {
            const int kt = (t + 1) * 64;
            #pragma unroll
            for (int i = 0; i < 2; i++) {
                int rg = wave * 2 + i;
                gload_lds16(kb + (size_t)(kt + rg * 8 + srow) * rs + scol,
                            &sK[buf ^ 1][rg * 512 + lane * 8]);
            }
            const unsigned short* vsrc = vb + (size_t)(kt + vkv) * rs + vd0;
            pv0 = *(const usx8*)vsrc;
            pv1 = *(const usx8*)(vsrc + 8);
        }

        // ---- QK^T swapped: sacc[n] holds S[kv = n*16+fq*4+j][q = fr]
        fx4 sacc[4];
        #pragma unroll
        for (int n = 0; n < 4; n++) sacc[n] = (fx4)0.0f;
        #pragma unroll
        for (int s = 0; s < 2; s++)
            #pragma unroll
            for (int n = 0; n < 4; n++) {
                bfx8 kF = *(const bfx8*)&sK[buf][(n * 16 + fr) * 64 + (((s * 4 + fq) ^ (fr & 7)) * 8)];
                sacc[n] = __builtin_amdgcn_mfma_f32_16x16x32_bf16(kF, qF[s], sacc[n], 0, 0, 0);
            }

        // ---- online softmax, lane-local for q=fr (reduce over fq: masks 16,32)
        float smax = sacc[0][0];
        #pragma unroll
        for (int n = 0; n < 4; n++)
            #pragma unroll
            for (int j = 0; j < 4; j++) smax = fmaxf(smax, sacc[n][j]);
        smax = fmaxf(smax, __shfl_xor(smax, 16));
        smax = fmaxf(smax, __shfl_xor(smax, 32));
        float mnew = fmaxf(m_run, smax);
        float scal = exp2f(m_run - mnew);
        float p[4][4];
        float ps = 0.0f;
        #pragma unroll
        for (int n = 0; n < 4; n++)
            #pragma unroll
            for (int j = 0; j < 4; j++) { p[n][j] = exp2f(sacc[n][j] - mnew); ps += p[n][j]; }
        ps += __shfl_xor(ps, 16);
        ps += __shfl_xor(ps, 32);
        l_run = l_run * scal + ps;
        m_run = mnew;
        #pragma unroll
        for (int db = 0; db < 4; db++) oacc[db] *= scal;

        // ---- pack P to bf16 pairs, butterfly into PV B-operand layout
        unsigned int u[4][2];
        #pragma unroll
        for (int n = 0; n < 4; n++)
            #pragma unroll
            for (int h = 0; h < 2; h++)
                u[n][h] = (unsigned int)f2bf(p[n][2 * h]) | ((unsigned int)f2bf(p[n][2 * h + 1]) << 16);
        unsigned int y[2][2], rA[2][2];
        #pragma unroll
        for (int m = 0; m < 2; m++)
            #pragma unroll
            for (int h = 0; h < 2; h++) {
                y[m][h] = f1 ? u[2 * m + 1][h] : u[2 * m][h];
                unsigned int x = f1 ? u[2 * m][h] : u[2 * m + 1][h];
                rA[m][h] = __shfl_xor((int)x, 32);
            }
        unsigned int w[2][4];
        #pragma unroll
        for (int m = 0; m < 2; m++)
            #pragma unroll
            for (int h = 0; h < 2; h++) {
                unsigned int kp = (f1 == f0) ? y[m][h] : rA[m][h];
                unsigned int z  = (f1 != f0) ? y[m][h] : rA[m][h];
                unsigned int rc = __shfl_xor((int)z, 16);
                w[m][h]     = f0 ? rc : kp;
                w[m][2 + h] = f0 ? kp : rc;
            }

        // ---- V prefetch writes (after loads have had QK+softmax to cover latency)
        if (pf) {
            #pragma unroll
            for (int j = 0; j < 8; j++) {
                sVt[buf ^ 1][vd0 + j][vkv]     = pv0[j];
                sVt[buf ^ 1][vd0 + 8 + j][vkv] = pv1[j];
            }
        }

        // ---- PV swapped: oacc[db] = O^T[d = db*16+fq*4+j][q = fr]
        #pragma unroll
        for (int s = 0; s < 2; s++) {
            union { unsigned int ui[4]; bfx8 bf; } cv;
            cv.ui[0] = w[s][0]; cv.ui[1] = w[s][1]; cv.ui[2] = w[s][2]; cv.ui[3] = w[s][3];
            #pragma unroll
            for (int db = 0; db < 4; db++) {
                bfx8 vF = *(const bfx8*)&sVt[buf][db * 16 + fr][s * 32 + fq * 8];
                oacc[db] = __builtin_amdgcn_mfma_f32_16x16x32_bf16(vF, cv.bf, oacc[db], 0, 0, 0);
            }
        }
    }

    // ---- epilogue: O^T in regs -> ao row-major
    float invl = 1.0f / l_run;
    const int qrow = qt * 64 + wave * 16 + fr;
    unsigned short* aop = ao + (size_t)(b * TLEN + qrow) * 1024 + hh * 64 + fq * 4;
    #pragma unroll
    for (int db = 0; db < 4; db++) {
        usx4 o4;
        #pragma unroll
        for (int j = 0; j < 4; j++) o4[j] = f2bf(oacc[db][j] * invl);
        *(usx4*)(aop + db * 16) = o4;
    }
}

extern "C" void kernel_launch(void* const* d_in, const int* in_sizes, int n_in,
                              void* d_out, int out_size, void* d_ws, size_t ws_size,
                              hipStream_t stream) {
    const float* x    = (const float*)d_in[0];
    const float* wq   = (const float*)d_in[1];
    const float* wk   = (const float*)d_in[2];
    const float* wv   = (const float*)d_in[3];
    const float* wo   = (const float*)d_in[4];
    const float* lng  = (const float*)d_in[5];
    const float* lnb  = (const float*)d_in[6];
    const float* cosT = (const float*)d_in[7];
    const float* sinT = (const float*)d_in[8];

    char* ws = (char*)d_ws;
    unsigned short* wqkv = (unsigned short*)(ws);                // 6 MB  [3072][1024] bf16
    unsigned short* wob  = (unsigned short*)(ws + (6u << 20));   // 2 MB  [1024][1024] bf16
    unsigned short* hbuf = (unsigned short*)(ws + (8u << 20));   // 8 MB  [4096][1024] bf16
    unsigned short* qkv  = (unsigned short*)(ws + (16u << 20));  // 24 MB [4096][3072] bf16
    unsigned short* ao   = (unsigned short*)(ws + (8u << 20));   // aliases hbuf (dead after QKV GEMM)

    ln_kernel<<<ROWS, 256, 0, stream>>>(x, lng, lnb, hbuf);
    wconv_kernel<<<1024, 256, 0, stream>>>(wq, wk, wv, wo, wqkv, wob);
    gemm_bt<0><<<dim3(32, 24), 256, 0, stream>>>(hbuf, wqkv, qkv, 3072);
    rope_kernel<<<8192, 256, 0, stream>>>(qkv, cosT, sinT);
    attn_kernel<<<dim3(32, 32), 256, 0, stream>>>(qkv, ao);
    gemm_bt<1><<<dim3(32, 8), 256, 0, stream>>>(ao, wob, (float*)d_out, 1024);
}